// Round 1
// baseline (357.880 us; speedup 1.0000x reference)
//
#include <hip/hip_runtime.h>
#include <math.h>

#define H_HEADS 33
#define C_CH    16
#define HC      528      // H_HEADS * C_CH
#define F_IN    128
#define NEG_SLOPE 0.2f

typedef short  bf16x8  __attribute__((ext_vector_type(8)));
typedef float  floatx4 __attribute__((ext_vector_type(4)));

__device__ inline unsigned short f2bf(float f) {   // RNE float->bf16
    unsigned int u = __float_as_uint(f);
    unsigned int r = u + 0x7fffu + ((u >> 16) & 1u);
    return (unsigned short)(r >> 16);
}
__device__ inline float bf2f(unsigned short u) {
    return __uint_as_float((unsigned int)u << 16);
}

// ---------------------------------------------------------------------------
// K0: Wt = bf16(W^T), [528][128].
// ---------------------------------------------------------------------------
__global__ void cvt_w_kernel(const float* __restrict__ W,
                             unsigned short* __restrict__ Wt)
{
    int g = blockIdx.x * blockDim.x + threadIdx.x;
    if (g >= F_IN * HC) return;
    int k = g / HC, n = g % HC;
    Wt[n * F_IN + k] = f2bf(W[g]);
}

// ---------------------------------------------------------------------------
// K1: h = x @ W via MFMA 16x16x32 bf16. One block per 64 rows; the block
// stages the f32 x-tile ONCE (converting to bf16 in staging -> no cvt_x
// pass), keeps A fragments in registers, and loops the 11 head-groups
// (BN=48 = 3 heads) internally. Wt (135KB) is L2-resident across blocks.
// Fused epilogue emits a_src/a_dst from the fp32 accumulators.
// ---------------------------------------------------------------------------
#define LDA 136
__global__ __launch_bounds__(256) void gemm_att_kernel(
    const float* __restrict__ x, const unsigned short* __restrict__ Wt,
    const float* __restrict__ att_src, const float* __restrict__ att_dst,
    unsigned short* __restrict__ hb,
    float* __restrict__ a_src, float* __restrict__ a_dst, int N)
{
    __shared__ unsigned short As[64][LDA];   // As[m][k]
    __shared__ unsigned short Bs[48][LDA];   // Bs[n][k] (= Wt rows)

    const int tid  = threadIdx.x;
    const int lane = tid & 63;
    const int wave = tid >> 6;
    const int lm   = lane & 15;
    const int kc   = lane >> 4;
    const int m0   = blockIdx.x * 64;

    // stage As from f32 x, converting: 64 rows x 32 float4 chunks
    for (int e = tid; e < 64 * 32; e += 256) {
        int r = e >> 5, c = e & 31;
        int gr = m0 + r;
        float4 v = (gr < N) ? ((const float4*)(x + (size_t)gr * F_IN))[c]
                            : make_float4(0.f, 0.f, 0.f, 0.f);
        unsigned int lo = (unsigned int)f2bf(v.x) | ((unsigned int)f2bf(v.y) << 16);
        unsigned int hi = (unsigned int)f2bf(v.z) | ((unsigned int)f2bf(v.w) << 16);
        *(uint2*)&As[r][c * 4] = make_uint2(lo, hi);
    }
    __syncthreads();

    // A fragments live in registers across all 11 head-group iterations
    const int arow = wave * 16 + lm;
    bf16x8 afrag[4];
    #pragma unroll
    for (int ks = 0; ks < 4; ++ks)
        afrag[ks] = *(const bf16x8*)&As[arow][ks * 32 + kc * 8];

    #pragma unroll 1
    for (int j = 0; j < 11; ++j) {
        __syncthreads();   // previous iteration's Bs reads done
        for (int e = tid; e < 48 * 16; e += 256) {
            int r = e >> 4, c = e & 15;
            uint4 v = ((const uint4*)(Wt + (size_t)(j * 48 + r) * F_IN))[c];
            *(uint4*)&Bs[r][c * 8] = v;
        }
        __syncthreads();

        floatx4 acc[3] = {};
        #pragma unroll
        for (int ks = 0; ks < 4; ++ks) {
            #pragma unroll
            for (int t = 0; t < 3; ++t) {
                bf16x8 b = *(const bf16x8*)&Bs[t * 16 + lm][ks * 32 + kc * 8];
                acc[t] = __builtin_amdgcn_mfma_f32_16x16x32_bf16(afrag[ks], b, acc[t], 0, 0, 0);
            }
        }

        // C/D layout: col = lane&15, row = (lane>>4)*4 + reg
        #pragma unroll
        for (int t = 0; t < 3; ++t) {
            const int head = j * 3 + t;
            const float w_s = att_src[head * C_CH + lm];
            const float w_d = att_dst[head * C_CH + lm];
            #pragma unroll
            for (int rr = 0; rr < 4; ++rr) {
                const int row = m0 + wave * 16 + kc * 4 + rr;
                float s = acc[t][rr] * w_s;
                float d = acc[t][rr] * w_d;
                #pragma unroll
                for (int m = 8; m >= 1; m >>= 1) {   // reduce across the 16 lm lanes
                    s += __shfl_xor(s, m);
                    d += __shfl_xor(d, m);
                }
                if (row < N) {
                    hb[(size_t)row * HC + j * 48 + t * 16 + lm] = f2bf(acc[t][rr]);
                    if (lm == 0) {
                        a_src[row * H_HEADS + head] = s;
                        a_dst[row * H_HEADS + head] = d;
                    }
                }
            }
        }
    }
}

// ---------------------------------------------------------------------------
// Counting sort of edges by src (incl. appended self loops) so that the
// aggregate pass's h[src] gather has L1/L2 locality.
// ---------------------------------------------------------------------------
__global__ void hist_kernel(const int* __restrict__ ei, int* __restrict__ hist,
                            int E, int Et)
{
    int g = blockIdx.x * blockDim.x + threadIdx.x;
    if (g >= Et) return;
    int src = (g < E) ? ei[g] : g - E;
    atomicAdd(&hist[src], 1);
}

// exclusive scan of hist[n] -> offs[n], single block of 1024
__global__ __launch_bounds__(1024) void scan_kernel(const int* __restrict__ hist,
                                                    int* __restrict__ offs, int n)
{
    __shared__ int warp_sums[16];
    __shared__ int s_carry;
    const int tid  = threadIdx.x;
    const int lane = tid & 63, wid = tid >> 6;
    if (tid == 0) s_carry = 0;
    __syncthreads();
    for (int base = 0; base < n; base += 1024) {
        int i = base + tid;
        int v = (i < n) ? hist[i] : 0;
        int s = v;
        #pragma unroll
        for (int d = 1; d < 64; d <<= 1) {
            int t = __shfl_up(s, d);
            if (lane >= d) s += t;
        }
        if (lane == 63) warp_sums[wid] = s;
        __syncthreads();
        if (tid < 16) {
            int ws = warp_sums[tid];
            #pragma unroll
            for (int d = 1; d < 16; d <<= 1) {
                int t = __shfl_up(ws, d);
                if (tid >= d) ws += t;
            }
            warp_sums[tid] = ws;
        }
        __syncthreads();
        int carry = s_carry;
        if (i < n) offs[i] = carry + (wid ? warp_sums[wid - 1] : 0) + (s - v);
        __syncthreads();
        if (tid == 0) s_carry = carry + warp_sums[15];
        __syncthreads();
    }
}

__global__ void scatter_kernel(const int* __restrict__ ei, int* __restrict__ cursor,
                               int* __restrict__ es, int* __restrict__ ed,
                               int E, int Et)
{
    int g = blockIdx.x * blockDim.x + threadIdx.x;
    if (g >= Et) return;
    int src, dst;
    if (g < E) { src = ei[g]; dst = ei[E + g]; }
    else       { src = dst = g - E; }
    int pos = atomicAdd(&cursor[src], 1);
    es[pos] = src;
    ed[pos] = dst;
}

// ---------------------------------------------------------------------------
// K2: denom[dst,hd] += exp(leakyrelu(a_src[src,hd] + a_dst[dst,hd]))
//     segment-max skipped: |e| small -> exp() safe; softmax shift-invariant.
//     Uses src-sorted edges: a_src gather is cache-local.
// ---------------------------------------------------------------------------
__global__ void denom_kernel(const int* __restrict__ es, const int* __restrict__ ed,
                             const float* __restrict__ a_src,
                             const float* __restrict__ a_dst,
                             float* __restrict__ denom, int Et)
{
    int g = blockIdx.x * blockDim.x + threadIdx.x;
    if (g >= Et * H_HEADS) return;
    int e  = g / H_HEADS;
    int hd = g - e * H_HEADS;
    int src = es[e], dst = ed[e];
    float v = a_src[src * H_HEADS + hd] + a_dst[dst * H_HEADS + hd];
    v = v > 0.f ? v : NEG_SLOPE * v;
    atomicAdd(&denom[dst * H_HEADS + hd], __expf(v));
}

// ---------------------------------------------------------------------------
// K3: 64 src-sorted edges/block. Phase 1: 64x33 alphas into LDS (inv folded).
// Phase 2: lane (edge,c) gathers bf16 h row (same src row repeats across
// consecutive edges -> L1 hits), fma with LDS alpha, one atomic per (edge,c).
// Bijective XCD-chunk swizzle keeps a src run on one XCD's L2.
// ---------------------------------------------------------------------------
#define EPB 64
__global__ __launch_bounds__(256) void aggregate_kernel(
    const int* __restrict__ es, const int* __restrict__ ed,
    const float* __restrict__ a_src, const float* __restrict__ a_dst,
    const float* __restrict__ denom,
    const unsigned short* __restrict__ hb,
    float* __restrict__ out, int Et)
{
    __shared__ int   s_src[EPB], s_dst[EPB];
    __shared__ float s_alpha[EPB][H_HEADS];

    // bijective XCD-chunked block swizzle (m204 formula)
    const int nwg = gridDim.x;
    const int q = nwg >> 3, r = nwg & 7;
    const int xcd = blockIdx.x & 7, idx = blockIdx.x >> 3;
    const int bid = (xcd < r ? xcd * (q + 1) : r * (q + 1) + (xcd - r) * q) + idx;

    const int tid = threadIdx.x;
    const int e0  = bid * EPB;

    if (tid < EPB * 2) {
        int el = tid & (EPB - 1);
        int e  = e0 + el;
        int v  = 0;
        if (e < Et) v = (tid < EPB) ? es[e] : ed[e];
        if (tid < EPB) s_src[el] = v; else s_dst[el] = v;
    }
    __syncthreads();

    for (int i = tid; i < EPB * H_HEADS; i += 256) {
        int el = i / H_HEADS, hd = i - el * H_HEADS;
        if (e0 + el < Et) {
            int src = s_src[el], dst = s_dst[el];
            float v = a_src[src * H_HEADS + hd] + a_dst[dst * H_HEADS + hd];
            v = v > 0.f ? v : NEG_SLOPE * v;
            s_alpha[el][hd] = __expf(v) / (denom[dst * H_HEADS + hd] + 1e-16f);
        }
    }
    __syncthreads();

    const int elq = tid >> 4, c = tid & 15;
    for (int el = elq; el < EPB; el += 16) {
        int e = e0 + el;
        if (e >= Et) break;
        int src = s_src[el], dst = s_dst[el];
        const unsigned short* hs = hb + (size_t)src * HC + c;
        float acc = 0.f;
        #pragma unroll
        for (int hd = 0; hd < H_HEADS; ++hd)
            acc += s_alpha[el][hd] * bf2f(hs[hd * C_CH]);
        atomicAdd(&out[dst * C_CH + c], acc);
    }
}

// K4: out = tanh(out/H + bias), in place
__global__ void finalize_kernel(float* __restrict__ out,
                                const float* __restrict__ bias, int total)
{
    int g = blockIdx.x * blockDim.x + threadIdx.x;
    if (g >= total) return;
    out[g] = tanhf(out[g] * (1.0f / 33.0f) + bias[g & 15]);
}

// ---------------------------------------------------------------------------
extern "C" void kernel_launch(void* const* d_in, const int* in_sizes, int n_in,
                              void* d_out, int out_size, void* d_ws, size_t ws_size,
                              hipStream_t stream)
{
    const float* x       = (const float*)d_in[0];
    const int*   ei      = (const int*)  d_in[1];
    const float* W       = (const float*)d_in[2];
    const float* att_src = (const float*)d_in[3];
    const float* att_dst = (const float*)d_in[4];
    const float* bias    = (const float*)d_in[5];
    float* out = (float*)d_out;

    const int N  = in_sizes[0] / F_IN;   // 50000
    const int E  = in_sizes[1] / 2;      // 320000
    const int Et = E + N;                // with self loops

    // workspace: hb (52.8MB) | a_src | a_dst | denom (3x6.6MB) |
    //            es | ed (2x1.48MB) | hist | cursor (2x0.2MB) | Wt (135KB)
    unsigned short* hb = (unsigned short*)d_ws;
    float* a_src  = (float*)(hb + (size_t)N * HC);
    float* a_dst  = a_src + (size_t)N * H_HEADS;
    float* denom  = a_dst + (size_t)N * H_HEADS;
    int*   es     = (int*)(denom + (size_t)N * H_HEADS);
    int*   ed     = es + Et;
    int*   hist   = ed + Et;
    int*   cursor = hist + N;
    unsigned short* Wt = (unsigned short*)(cursor + N);

    hipMemsetAsync(d_out, 0, (size_t)out_size * sizeof(float), stream);
    hipMemsetAsync(denom, 0, (size_t)N * H_HEADS * sizeof(float), stream);
    hipMemsetAsync(hist, 0, (size_t)N * sizeof(int), stream);

    cvt_w_kernel<<<(F_IN * HC + 255) / 256, 256, 0, stream>>>(W, Wt);

    gemm_att_kernel<<<(N + 63) / 64, 256, 0, stream>>>(x, Wt, att_src, att_dst,
                                                       hb, a_src, a_dst, N);

    hist_kernel<<<(Et + 255) / 256, 256, 0, stream>>>(ei, hist, E, Et);
    scan_kernel<<<1, 1024, 0, stream>>>(hist, cursor, N);
    scatter_kernel<<<(Et + 255) / 256, 256, 0, stream>>>(ei, cursor, es, ed, E, Et);

    int totD = Et * H_HEADS;
    denom_kernel<<<(totD + 255) / 256, 256, 0, stream>>>(es, ed, a_src, a_dst,
                                                         denom, Et);

    aggregate_kernel<<<(Et + EPB - 1) / EPB, 256, 0, stream>>>(
        es, ed, a_src, a_dst, denom, hb, out, Et);

    int totO = N * C_CH;
    finalize_kernel<<<(totO + 255) / 256, 256, 0, stream>>>(out, bias, totO);
}